// Round 19
// baseline (285.343 us; speedup 1.0000x reference)
//
#include <hip/hip_runtime.h>
#include <hip/hip_bf16.h>

// Round 19: r18 (280us) + cross-barrier prefetch of GEMM1(it+1)'s first two
// K-steps (aF kk=0,1 from read-only xnp LDS; bF kk=0,1 from global wqp) during
// phase 2. GEMM1 opens with 24 register-ready MFMAs covering the kk>=2 load
// latency. Prologue does the same for it=0 after the LN barrier.

#define NTOK  64
#define CCH   384
#define NH    12
#define HD    32
#define EPSV  1e-5f
#define SCALEQ 0.17677669529663687f   // 1/sqrt(32)

#define WQP_ELEMS (72 * 12 * 64 * 8)      // 442368 bf16
#define WOP_ELEMS (24 * 12 * 64 * 8)      // 147456 bf16
#define BLUTP_ELEMS (12 * 4 * 4 * 64 * 4) // 196608 f32

typedef __attribute__((ext_vector_type(8))) short  short8;
typedef __attribute__((ext_vector_type(4))) short  short4v;
typedef __attribute__((ext_vector_type(4))) float  float4v;
typedef __attribute__((ext_vector_type(4))) int    int4v;

__device__ __forceinline__ unsigned short f2bf(float f) {
    union { float f; unsigned int i; } v; v.f = f;
    unsigned int r = v.i + 0x7fffu + ((v.i >> 16) & 1u);   // RNE
    return (unsigned short)(r >> 16);
}
__device__ __forceinline__ unsigned int pack2bf(float lo, float hi) {
    return (unsigned int)f2bf(lo) | ((unsigned int)f2bf(hi) << 16);
}
__device__ __forceinline__ short4v pack4bf(float a, float b, float c, float d) {
    short4v p;
    p[0] = (short)f2bf(a); p[1] = (short)f2bf(b);
    p[2] = (short)f2bf(c); p[3] = (short)f2bf(d);
    return p;
}

__global__ void prep_kernel(const float* __restrict__ w_qkv_f,
                            const float* __restrict__ w_out_f,
                            const float* __restrict__ bias_tab,
                            const int*   __restrict__ rel_idx,
                            unsigned short* __restrict__ wqp,
                            unsigned short* __restrict__ wop,
                            float* __restrict__ blutp) {
    const int stride = gridDim.x * blockDim.x;
    const int tid = blockIdx.x * blockDim.x + threadIdx.x;
    for (int i = tid; i < WQP_ELEMS; i += stride) {
        const int t = i / 6144, rem = i % 6144;
        const int kk = rem >> 9, rem2 = rem & 511;
        const int lane = rem2 >> 3, e = rem2 & 7;
        wqp[i] = f2bf(w_qkv_f[(16 * t + (lane & 15)) * CCH + 32 * kk + 8 * (lane >> 4) + e]);
    }
    for (int i = tid; i < WOP_ELEMS; i += stride) {
        const int t = i / 6144, rem = i % 6144;
        const int kk = rem >> 9, rem2 = rem & 511;
        const int lane = rem2 >> 3, e = rem2 & 7;
        wop[i] = f2bf(w_out_f[(16 * t + (lane & 15)) * CCH + 32 * kk + 8 * (lane >> 4) + e]);
    }
    for (int i = tid; i < BLUTP_ELEMS; i += stride) {
        const int r = i & 3, lane = (i >> 2) & 63;
        const int kt = (i >> 8) & 3, tt = (i >> 10) & 3, h = i >> 12;
        const int token = 16 * tt + (lane & 15);
        const int key   = 16 * kt + 4 * (lane >> 4) + r;
        blutp[i] = bias_tab[rel_idx[token * 64 + key] * NH + h];
    }
}

__global__ __launch_bounds__(512, 2)
void fused_win_mha(const float* __restrict__ x,
                   const float* __restrict__ ln_g,
                   const float* __restrict__ ln_b,
                   const float* __restrict__ b_out,
                   const unsigned short* __restrict__ wqp,
                   const unsigned short* __restrict__ wop,
                   const float* __restrict__ blutp,
                   float* __restrict__ out)
{
    const int b    = blockIdx.x;
    const int t    = threadIdx.x;
    const int wav  = t >> 6;        // 0..7
    const int lane = t & 63;
    const int l4   = lane >> 4;     // 0..3
    const int lc   = lane & 15;     // 0..15
    const int lh   = wav >> 1;      // 0..3 head-local
    const int mh   = wav & 1;       // 0..1 half (dims 16mh..16mh+15 of each head)

    __shared__ unsigned short xnp[4 * 12 * 64 * 8];      // 49152 B  A/B-frags of xn (read-only after LN)
    __shared__ unsigned short qp [4 * 4 * 64 * 8];       // 16384 B  B-frags of q
    __shared__ unsigned short kp [4 * 4 * 64 * 8];       // 16384 B  A-frags of k
    __shared__ unsigned short vp [2][4 * 2 * 2 * 64 * 8];// 32768 B  B-frags of v (dbuf)
    __shared__ unsigned short attp[4 * 4 * 64 * 8];      // 16384 B  A-frags of att
    // total 131072 B -> 1 block/CU

    // ---------------- LayerNorm (f32 x -> bf16 xnp, packed) ----------------
    {
        const int row = t >> 3, seg = t & 7;
        const float* xr = x + (b * NTOK + row) * CCH + seg * 48;
        float vals[48];
        float s = 0.f, s2 = 0.f;
        #pragma unroll
        for (int i = 0; i < 12; ++i) {
            float4v v = *(const float4v*)(xr + i * 4);
            #pragma unroll
            for (int j = 0; j < 4; ++j) {
                float f = v[j];
                vals[i * 4 + j] = f; s += f; s2 += f * f;
            }
        }
        s += __shfl_xor(s, 1); s2 += __shfl_xor(s2, 1);
        s += __shfl_xor(s, 2); s2 += __shfl_xor(s2, 2);
        s += __shfl_xor(s, 4); s2 += __shfl_xor(s2, 4);
        const float mu   = s * (1.f / CCH);
        const float rstd = rsqrtf(s2 * (1.f / CCH) - mu * mu + EPSV);
        #pragma unroll
        for (int u = 0; u < 6; ++u) {
            const int col0 = seg * 48 + u * 8;
            short8 w;
            #pragma unroll
            for (int e2 = 0; e2 < 2; ++e2) {
                float4v gv = *(const float4v*)(ln_g + col0 + e2 * 4);
                float4v bv = *(const float4v*)(ln_b + col0 + e2 * 4);
                #pragma unroll
                for (int j = 0; j < 4; ++j)
                    w[e2 * 4 + j] = (short)f2bf((vals[u * 8 + e2 * 4 + j] - mu) * rstd * gv[j] + bv[j]);
            }
            const int idx = ((((row >> 4) * 12 + (col0 >> 5)) << 9)
                             + ((((col0 >> 3) & 3) * 16 + (row & 15)) << 3));
            *(short8*)&xnp[idx] = w;
        }
    }
    __syncthreads();

    float4v facc[4][3];
    #pragma unroll
    for (int mt = 0; mt < 4; ++mt)
        #pragma unroll
        for (int j = 0; j < 3; ++j)
            facc[mt][j] = (float4v){0.f, 0.f, 0.f, 0.f};

    float sv[2][4][4];   // biased scores (group it-1) carried across iterations
    float mx[2];
    float4v bbn[2][4];   // prefetched bias for group it
    short8 aF01[2][4], bF01[2][3];   // prefetched GEMM1 kk=0,1 operands for group it

    // prologue prefetch for it=0
    {
        #pragma unroll
        for (int kk = 0; kk < 2; ++kk) {
            #pragma unroll
            for (int mt = 0; mt < 4; ++mt)
                aF01[kk][mt] = *(const short8*)&xnp[((mt * 12 + kk) << 9) + (lane << 3)];
            #pragma unroll
            for (int n = 0; n < 3; ++n) {
                const int tile = n * 24 + lh * 2 + mh;
                bF01[kk][n] = *(const short8*)&wqp[((tile * 12 + kk) << 9) + (lane << 3)];
            }
        }
    }

    #pragma unroll
    for (int it = 0; it < 4; ++it) {
        // ================= FUSED PHASE =================
        // ---------- bG prefetch for GEMM2(it-1) (global, no hazard) ----------
        short8 bGb[4][3];
        if (it > 0) {
            const int g = it - 1;
            #pragma unroll
            for (int ks = 0; ks < 4; ++ks)
                #pragma unroll
                for (int j2 = 0; j2 < 3; ++j2)
                    bGb[ks][j2] = *(const short8*)&wop[(((3 * wav + j2) * 12 + 4 * g + ks) << 9) + (lane << 3)];
        }
        // ---------- bias prefetch for group it ----------
        if (it < 3) {
            const int h = 4 * it + lh;
            #pragma unroll
            for (int j = 0; j < 2; ++j)
                #pragma unroll
                for (int kt = 0; kt < 4; ++kt)
                    bbn[j][kt] = *(const float4v*)(blutp + ((((h * 4 + (2 * mh + j)) * 4 + kt) << 6) + lane) * 4);
        }

        // ---------- softmax-finish(it-1) ----------
        short8 af[2][2];
        if (it > 0) {
            unsigned int pk2[2][4][2];
            #pragma unroll
            for (int j = 0; j < 2; ++j) {
                float sk[4];
                #pragma unroll
                for (int kt = 0; kt < 4; ++kt) {
                    float pe0 = __expf(sv[j][kt][0] - mx[j]);
                    float pe1 = __expf(sv[j][kt][1] - mx[j]);
                    float pe2 = __expf(sv[j][kt][2] - mx[j]);
                    float pe3 = __expf(sv[j][kt][3] - mx[j]);
                    sv[j][kt][0] = pe0; sv[j][kt][1] = pe1;
                    sv[j][kt][2] = pe2; sv[j][kt][3] = pe3;
                    sk[kt] = (pe0 + pe1) + (pe2 + pe3);
                }
                float s = (sk[0] + sk[1]) + (sk[2] + sk[3]);
                s += __shfl_xor(s, 16);
                s += __shfl_xor(s, 32);
                const float rinv = 1.f / s;
                #pragma unroll
                for (int kt = 0; kt < 4; ++kt) {
                    pk2[j][kt][0] = pack2bf(sv[j][kt][0] * rinv, sv[j][kt][1] * rinv);
                    pk2[j][kt][1] = pack2bf(sv[j][kt][2] * rinv, sv[j][kt][3] * rinv);
                }
            }
            const int src0 = lc + 16 * (2 * (l4 & 1));
            const int src1 = src0 + 16;
            const bool hi  = ((l4 >> 1) & 1) != 0;
            #pragma unroll
            for (int j = 0; j < 2; ++j) {
                #pragma unroll
                for (int kk2 = 0; kk2 < 2; ++kk2) {
                    const int ka = 2 * kk2, kb = 2 * kk2 + 1;
                    unsigned int a0a = (unsigned int)__shfl((int)pk2[j][ka][0], src0);
                    unsigned int a0b = (unsigned int)__shfl((int)pk2[j][kb][0], src0);
                    unsigned int a1a = (unsigned int)__shfl((int)pk2[j][ka][1], src0);
                    unsigned int a1b = (unsigned int)__shfl((int)pk2[j][kb][1], src0);
                    unsigned int a2a = (unsigned int)__shfl((int)pk2[j][ka][0], src1);
                    unsigned int a2b = (unsigned int)__shfl((int)pk2[j][kb][0], src1);
                    unsigned int a3a = (unsigned int)__shfl((int)pk2[j][ka][1], src1);
                    unsigned int a3b = (unsigned int)__shfl((int)pk2[j][kb][1], src1);
                    int4v iv;
                    iv[0] = (int)(hi ? a0b : a0a);
                    iv[1] = (int)(hi ? a1b : a1a);
                    iv[2] = (int)(hi ? a2b : a2a);
                    iv[3] = (int)(hi ? a3b : a3a);
                    af[j][kk2] = __builtin_bit_cast(short8, iv);
                }
            }
        }

        // ---------- GEMM1(it): kk=0,1 from prefetched regs; kk>=2 streamed ----------
        float4v acc[3][4];
        int tile_[3];
        if (it < 3) {
            const int h = 4 * it + lh;
            #pragma unroll
            for (int n = 0; n < 3; ++n) {
                tile_[n] = n * 24 + h * 2 + mh;   // mat=n (q,k,v), half=mh
                #pragma unroll
                for (int m = 0; m < 4; ++m)
                    acc[n][m] = (float4v){0.f, 0.f, 0.f, 0.f};
            }
            #pragma unroll
            for (int kk = 0; kk < 12; ++kk) {
                short8 aF[4], bF0, bF1, bF2;
                if (kk < 2) {
                    #pragma unroll
                    for (int mt = 0; mt < 4; ++mt) aF[mt] = aF01[kk][mt];
                    bF0 = bF01[kk][0]; bF1 = bF01[kk][1]; bF2 = bF01[kk][2];
                } else {
                    #pragma unroll
                    for (int mt = 0; mt < 4; ++mt)
                        aF[mt] = *(const short8*)&xnp[((mt * 12 + kk) << 9) + (lane << 3)];
                    bF0 = *(const short8*)&wqp[((tile_[0] * 12 + kk) << 9) + (lane << 3)];
                    bF1 = *(const short8*)&wqp[((tile_[1] * 12 + kk) << 9) + (lane << 3)];
                    bF2 = *(const short8*)&wqp[((tile_[2] * 12 + kk) << 9) + (lane << 3)];
                }
                #pragma unroll
                for (int mt = 0; mt < 4; ++mt) {
                    // q,k: swapped (C: row=dim-local, col=token) -> b64 scatter
                    acc[0][mt] = __builtin_amdgcn_mfma_f32_16x16x32_bf16(bF0, aF[mt], acc[0][mt], 0, 0, 0);
                    acc[1][mt] = __builtin_amdgcn_mfma_f32_16x16x32_bf16(bF1, aF[mt], acc[1][mt], 0, 0, 0);
                    // v: normal (C: row=token, col=dim) -> b64 vT scatter
                    acc[2][mt] = __builtin_amdgcn_mfma_f32_16x16x32_bf16(aF[mt], bF2, acc[2][mt], 0, 0, 0);
                }
            }
        }

        // ---------- PV(it-1): swapped (o = mfma(V, P)) + b64 attp write ----------
        if (it > 0) {
            const unsigned short* vpr = vp[(it - 1) & 1];
            float4v o[2][2];
            #pragma unroll
            for (int j = 0; j < 2; ++j)
                #pragma unroll
                for (int nt = 0; nt < 2; ++nt)
                    o[j][nt] = (float4v){0.f, 0.f, 0.f, 0.f};
            #pragma unroll
            for (int kk2 = 0; kk2 < 2; ++kk2) {
                #pragma unroll
                for (int nt = 0; nt < 2; ++nt) {
                    short8 vf = *(const short8*)&vpr[(((lh * 2 + nt) * 2 + kk2) << 9) + (lane << 3)];
                    #pragma unroll
                    for (int j = 0; j < 2; ++j)
                        o[j][nt] = __builtin_amdgcn_mfma_f32_16x16x32_bf16(vf, af[j][kk2], o[j][nt], 0, 0, 0);
                }
            }
            // o[j][nt]: row=dim 16nt+4l4+r, col=token 16(2mh+j)+lc
            #pragma unroll
            for (int j = 0; j < 2; ++j) {
                #pragma unroll
                for (int nt = 0; nt < 2; ++nt) {
                    const int addr = (((2 * mh + j) * 4 + lh) << 9)
                                   + (((2 * nt + (l4 >> 1)) * 16 + lc) << 3)
                                   + ((l4 & 1) << 2);
                    *(short4v*)&attp[addr] = pack4bf(o[j][nt][0], o[j][nt][1], o[j][nt][2], o[j][nt][3]);
                }
            }
        }

        // ---------- scatter(it): all b64 ----------
        if (it < 3) {
            unsigned short* vpw = vp[it & 1];
            #pragma unroll
            for (int mt = 0; mt < 4; ++mt) {
                short4v pq, pkk, pv;
                #pragma unroll
                for (int r = 0; r < 4; ++r) {
                    pq[r]  = (short)f2bf(acc[0][mt][r] * SCALEQ);
                    pkk[r] = (short)f2bf(acc[1][mt][r]);
                    pv[r]  = (short)f2bf(acc[2][mt][r]);
                }
                const int aqk = ((lh * 4 + mt) << 9)
                              + (((2 * mh + (l4 >> 1)) * 16 + lc) << 3)
                              + ((l4 & 1) << 2);
                *(short4v*)&qp[aqk] = pq;
                *(short4v*)&kp[aqk] = pkk;
                const int av = (((lh * 2 + mh) * 2 + (mt >> 1)) << 9)
                             + ((((mt & 1) * 2 + (l4 >> 1)) * 16 + lc) << 3)
                             + ((l4 & 1) << 2);
                *(short4v*)&vpw[av] = pv;
            }
        }
        __syncthreads();   // barrier 1: attp(it-1) + qkv(it) visible

        // ================= PHASE 2 (register outputs + cross-barrier prefetch) =================
        // ---------- GEMM2(it-1) with prefetched bGb ----------
        if (it > 0) {
            #pragma unroll
            for (int ks = 0; ks < 4; ++ks) {
                short8 aG[4];
                #pragma unroll
                for (int mt = 0; mt < 4; ++mt)
                    aG[mt] = *(const short8*)&attp[((mt * 4 + ks) << 9) + (lane << 3)];
                #pragma unroll
                for (int j2 = 0; j2 < 3; ++j2)
                    #pragma unroll
                    for (int mt = 0; mt < 4; ++mt)
                        facc[mt][j2] = __builtin_amdgcn_mfma_f32_16x16x32_bf16(aG[mt], bGb[ks][j2], facc[mt][j2], 0, 0, 0);
            }
        }
        // ---------- QK(it) + bias + rowmax ----------
        if (it < 3) {
            #pragma unroll
            for (int j = 0; j < 2; ++j) {
                short8 qf = *(const short8*)&qp[((lh * 4 + (2 * mh + j)) << 9) + (lane << 3)];
                #pragma unroll
                for (int kt = 0; kt < 4; ++kt) {
                    short8 kf = *(const short8*)&kp[((lh * 4 + kt) << 9) + (lane << 3)];
                    float4v sres = __builtin_amdgcn_mfma_f32_16x16x32_bf16(
                        kf, qf, (float4v){0.f, 0.f, 0.f, 0.f}, 0, 0, 0);
                    #pragma unroll
                    for (int r = 0; r < 4; ++r) sv[j][kt][r] = sres[r];
                }
            }
            #pragma unroll
            for (int j = 0; j < 2; ++j) {
                float m = -1e30f;
                #pragma unroll
                for (int kt = 0; kt < 4; ++kt) {
                    #pragma unroll
                    for (int r = 0; r < 4; ++r) {
                        sv[j][kt][r] += bbn[j][kt][r];
                        m = fmaxf(m, sv[j][kt][r]);
                    }
                }
                m = fmaxf(m, __shfl_xor(m, 16));
                m = fmaxf(m, __shfl_xor(m, 32));
                mx[j] = m;
            }
        }
        // ---------- cross-barrier prefetch: GEMM1(it+1) kk=0,1 (xnp read-only, wqp global) ----------
        if (it < 2) {
            const int hN = 4 * (it + 1) + lh;
            #pragma unroll
            for (int kk = 0; kk < 2; ++kk) {
                #pragma unroll
                for (int mt = 0; mt < 4; ++mt)
                    aF01[kk][mt] = *(const short8*)&xnp[((mt * 12 + kk) << 9) + (lane << 3)];
                #pragma unroll
                for (int n = 0; n < 3; ++n) {
                    const int tile = n * 24 + hN * 2 + mh;
                    bF01[kk][n] = *(const short8*)&wqp[((tile * 12 + kk) << 9) + (lane << 3)];
                }
            }
        }
        __syncthreads();   // barrier 2: attp/qp/kp reads done before next fused phase
    }

    // ---------------- epilogue ----------------
    {
        float* ob = out + b * (NTOK * CCH);
        #pragma unroll
        for (int mt = 0; mt < 4; ++mt) {
            #pragma unroll
            for (int j2 = 0; j2 < 3; ++j2) {
                const int c = 16 * (3 * wav + j2) + lc;
                const float bo = b_out[c];
                #pragma unroll
                for (int r = 0; r < 4; ++r)
                    ob[(16 * mt + 4 * l4 + r) * CCH + c] = facc[mt][j2][r] + bo;
            }
        }
    }
}

extern "C" void kernel_launch(void* const* d_in, const int* in_sizes, int n_in,
                              void* d_out, int out_size, void* d_ws, size_t ws_size,
                              hipStream_t stream) {
    const float* x     = (const float*)d_in[0];
    const float* ln_g  = (const float*)d_in[1];
    const float* ln_b  = (const float*)d_in[2];
    const float* w_qkv = (const float*)d_in[3];
    const float* w_out = (const float*)d_in[4];
    const float* b_out = (const float*)d_in[5];
    const float* btab  = (const float*)d_in[6];
    const int*   ridx  = (const int*)d_in[7];
    float*       out   = (float*)d_out;

    unsigned short* wqp   = (unsigned short*)d_ws;
    unsigned short* wop   = wqp + WQP_ELEMS;
    float*          blutp = (float*)(wop + WOP_ELEMS);   // byte offset 1179648, 16B-aligned

    prep_kernel<<<512, 256, 0, stream>>>(w_qkv, w_out, btab, ridx, wqp, wop, blutp);
    fused_win_mha<<<2048, 512, 0, stream>>>(x, ln_g, ln_b, b_out, wqp, wop, blutp, out);
}

// Round 20
// 280.069 us; speedup vs baseline: 1.0188x; 1.0188x over previous
//
#include <hip/hip_runtime.h>
#include <hip/hip_bf16.h>

// Round 20 = r18 verbatim (best measured: 280.6us). r19's extra prefetch caused
// spill (WRITE_SIZE 197->246MB) and regressed; r18 is the register-budget optimum.
// Structure: 512 thr / 8 waves / 1 block/CU; 2-barrier deferred-softmax pipeline;
// packed fragment-major LDS (conflict-free reads, all-b64 scatters); prep-packed
// coalesced weights; cross-barrier bG+bias register prefetch.

#define NTOK  64
#define CCH   384
#define NH    12
#define HD    32
#define EPSV  1e-5f
#define SCALEQ 0.17677669529663687f   // 1/sqrt(32)

#define WQP_ELEMS (72 * 12 * 64 * 8)      // 442368 bf16
#define WOP_ELEMS (24 * 12 * 64 * 8)      // 147456 bf16
#define BLUTP_ELEMS (12 * 4 * 4 * 64 * 4) // 196608 f32

typedef __attribute__((ext_vector_type(8))) short  short8;
typedef __attribute__((ext_vector_type(4))) short  short4v;
typedef __attribute__((ext_vector_type(4))) float  float4v;
typedef __attribute__((ext_vector_type(4))) int    int4v;

__device__ __forceinline__ unsigned short f2bf(float f) {
    union { float f; unsigned int i; } v; v.f = f;
    unsigned int r = v.i + 0x7fffu + ((v.i >> 16) & 1u);   // RNE
    return (unsigned short)(r >> 16);
}
__device__ __forceinline__ unsigned int pack2bf(float lo, float hi) {
    return (unsigned int)f2bf(lo) | ((unsigned int)f2bf(hi) << 16);
}
__device__ __forceinline__ short4v pack4bf(float a, float b, float c, float d) {
    short4v p;
    p[0] = (short)f2bf(a); p[1] = (short)f2bf(b);
    p[2] = (short)f2bf(c); p[3] = (short)f2bf(d);
    return p;
}

__global__ void prep_kernel(const float* __restrict__ w_qkv_f,
                            const float* __restrict__ w_out_f,
                            const float* __restrict__ bias_tab,
                            const int*   __restrict__ rel_idx,
                            unsigned short* __restrict__ wqp,
                            unsigned short* __restrict__ wop,
                            float* __restrict__ blutp) {
    const int stride = gridDim.x * blockDim.x;
    const int tid = blockIdx.x * blockDim.x + threadIdx.x;
    for (int i = tid; i < WQP_ELEMS; i += stride) {
        const int t = i / 6144, rem = i % 6144;
        const int kk = rem >> 9, rem2 = rem & 511;
        const int lane = rem2 >> 3, e = rem2 & 7;
        wqp[i] = f2bf(w_qkv_f[(16 * t + (lane & 15)) * CCH + 32 * kk + 8 * (lane >> 4) + e]);
    }
    for (int i = tid; i < WOP_ELEMS; i += stride) {
        const int t = i / 6144, rem = i % 6144;
        const int kk = rem >> 9, rem2 = rem & 511;
        const int lane = rem2 >> 3, e = rem2 & 7;
        wop[i] = f2bf(w_out_f[(16 * t + (lane & 15)) * CCH + 32 * kk + 8 * (lane >> 4) + e]);
    }
    for (int i = tid; i < BLUTP_ELEMS; i += stride) {
        const int r = i & 3, lane = (i >> 2) & 63;
        const int kt = (i >> 8) & 3, tt = (i >> 10) & 3, h = i >> 12;
        const int token = 16 * tt + (lane & 15);
        const int key   = 16 * kt + 4 * (lane >> 4) + r;
        blutp[i] = bias_tab[rel_idx[token * 64 + key] * NH + h];
    }
}

__global__ __launch_bounds__(512, 2)
void fused_win_mha(const float* __restrict__ x,
                   const float* __restrict__ ln_g,
                   const float* __restrict__ ln_b,
                   const float* __restrict__ b_out,
                   const unsigned short* __restrict__ wqp,
                   const unsigned short* __restrict__ wop,
                   const float* __restrict__ blutp,
                   float* __restrict__ out)
{
    const int b    = blockIdx.x;
    const int t    = threadIdx.x;
    const int wav  = t >> 6;        // 0..7
    const int lane = t & 63;
    const int l4   = lane >> 4;     // 0..3
    const int lc   = lane & 15;     // 0..15
    const int lh   = wav >> 1;      // 0..3 head-local
    const int mh   = wav & 1;       // 0..1 half (dims 16mh..16mh+15 of each head)

    __shared__ unsigned short xnp[4 * 12 * 64 * 8];      // 49152 B  A/B-frags of xn
    __shared__ unsigned short qp [4 * 4 * 64 * 8];       // 16384 B  B-frags of q
    __shared__ unsigned short kp [4 * 4 * 64 * 8];       // 16384 B  A-frags of k
    __shared__ unsigned short vp [2][4 * 2 * 2 * 64 * 8];// 32768 B  B-frags of v (dbuf)
    __shared__ unsigned short attp[4 * 4 * 64 * 8];      // 16384 B  A-frags of att
    // total 131072 B -> 1 block/CU

    // ---------------- LayerNorm (f32 x -> bf16 xnp, packed) ----------------
    {
        const int row = t >> 3, seg = t & 7;
        const float* xr = x + (b * NTOK + row) * CCH + seg * 48;
        float vals[48];
        float s = 0.f, s2 = 0.f;
        #pragma unroll
        for (int i = 0; i < 12; ++i) {
            float4v v = *(const float4v*)(xr + i * 4);
            #pragma unroll
            for (int j = 0; j < 4; ++j) {
                float f = v[j];
                vals[i * 4 + j] = f; s += f; s2 += f * f;
            }
        }
        s += __shfl_xor(s, 1); s2 += __shfl_xor(s2, 1);
        s += __shfl_xor(s, 2); s2 += __shfl_xor(s2, 2);
        s += __shfl_xor(s, 4); s2 += __shfl_xor(s2, 4);
        const float mu   = s * (1.f / CCH);
        const float rstd = rsqrtf(s2 * (1.f / CCH) - mu * mu + EPSV);
        #pragma unroll
        for (int u = 0; u < 6; ++u) {
            const int col0 = seg * 48 + u * 8;
            short8 w;
            #pragma unroll
            for (int e2 = 0; e2 < 2; ++e2) {
                float4v gv = *(const float4v*)(ln_g + col0 + e2 * 4);
                float4v bv = *(const float4v*)(ln_b + col0 + e2 * 4);
                #pragma unroll
                for (int j = 0; j < 4; ++j)
                    w[e2 * 4 + j] = (short)f2bf((vals[u * 8 + e2 * 4 + j] - mu) * rstd * gv[j] + bv[j]);
            }
            const int idx = ((((row >> 4) * 12 + (col0 >> 5)) << 9)
                             + ((((col0 >> 3) & 3) * 16 + (row & 15)) << 3));
            *(short8*)&xnp[idx] = w;
        }
    }
    __syncthreads();

    float4v facc[4][3];
    #pragma unroll
    for (int mt = 0; mt < 4; ++mt)
        #pragma unroll
        for (int j = 0; j < 3; ++j)
            facc[mt][j] = (float4v){0.f, 0.f, 0.f, 0.f};

    float sv[2][4][4];   // biased scores (group it-1) carried across iterations
    float mx[2];
    float4v bbn[2][4];   // prefetched bias for group it

    #pragma unroll
    for (int it = 0; it < 4; ++it) {
        // ================= FUSED PHASE =================
        // ---------- bG prefetch for GEMM2(it-1) (used in phase 2; global, no hazard) ----------
        short8 bGb[4][3];
        if (it > 0) {
            const int g = it - 1;
            #pragma unroll
            for (int ks = 0; ks < 4; ++ks)
                #pragma unroll
                for (int j2 = 0; j2 < 3; ++j2)
                    bGb[ks][j2] = *(const short8*)&wop[(((3 * wav + j2) * 12 + 4 * g + ks) << 9) + (lane << 3)];
        }
        // ---------- bias prefetch for group it ----------
        if (it < 3) {
            const int h = 4 * it + lh;
            #pragma unroll
            for (int j = 0; j < 2; ++j)
                #pragma unroll
                for (int kt = 0; kt < 4; ++kt)
                    bbn[j][kt] = *(const float4v*)(blutp + ((((h * 4 + (2 * mh + j)) * 4 + kt) << 6) + lane) * 4);
        }

        // ---------- softmax-finish(it-1) ----------
        short8 af[2][2];
        if (it > 0) {
            unsigned int pk2[2][4][2];
            #pragma unroll
            for (int j = 0; j < 2; ++j) {
                float sk[4];
                #pragma unroll
                for (int kt = 0; kt < 4; ++kt) {
                    float pe0 = __expf(sv[j][kt][0] - mx[j]);
                    float pe1 = __expf(sv[j][kt][1] - mx[j]);
                    float pe2 = __expf(sv[j][kt][2] - mx[j]);
                    float pe3 = __expf(sv[j][kt][3] - mx[j]);
                    sv[j][kt][0] = pe0; sv[j][kt][1] = pe1;
                    sv[j][kt][2] = pe2; sv[j][kt][3] = pe3;
                    sk[kt] = (pe0 + pe1) + (pe2 + pe3);
                }
                float s = (sk[0] + sk[1]) + (sk[2] + sk[3]);
                s += __shfl_xor(s, 16);
                s += __shfl_xor(s, 32);
                const float rinv = 1.f / s;
                #pragma unroll
                for (int kt = 0; kt < 4; ++kt) {
                    pk2[j][kt][0] = pack2bf(sv[j][kt][0] * rinv, sv[j][kt][1] * rinv);
                    pk2[j][kt][1] = pack2bf(sv[j][kt][2] * rinv, sv[j][kt][3] * rinv);
                }
            }
            const int src0 = lc + 16 * (2 * (l4 & 1));
            const int src1 = src0 + 16;
            const bool hi  = ((l4 >> 1) & 1) != 0;
            #pragma unroll
            for (int j = 0; j < 2; ++j) {
                #pragma unroll
                for (int kk2 = 0; kk2 < 2; ++kk2) {
                    const int ka = 2 * kk2, kb = 2 * kk2 + 1;
                    unsigned int a0a = (unsigned int)__shfl((int)pk2[j][ka][0], src0);
                    unsigned int a0b = (unsigned int)__shfl((int)pk2[j][kb][0], src0);
                    unsigned int a1a = (unsigned int)__shfl((int)pk2[j][ka][1], src0);
                    unsigned int a1b = (unsigned int)__shfl((int)pk2[j][kb][1], src0);
                    unsigned int a2a = (unsigned int)__shfl((int)pk2[j][ka][0], src1);
                    unsigned int a2b = (unsigned int)__shfl((int)pk2[j][kb][0], src1);
                    unsigned int a3a = (unsigned int)__shfl((int)pk2[j][ka][1], src1);
                    unsigned int a3b = (unsigned int)__shfl((int)pk2[j][kb][1], src1);
                    int4v iv;
                    iv[0] = (int)(hi ? a0b : a0a);
                    iv[1] = (int)(hi ? a1b : a1a);
                    iv[2] = (int)(hi ? a2b : a2a);
                    iv[3] = (int)(hi ? a3b : a3a);
                    af[j][kk2] = __builtin_bit_cast(short8, iv);
                }
            }
        }

        // ---------- GEMM1(it): parts {q,k,v} at half=mh; q,k swapped-operand ----------
        float4v acc[3][4];
        int tile_[3];
        if (it < 3) {
            const int h = 4 * it + lh;
            #pragma unroll
            for (int n = 0; n < 3; ++n) {
                tile_[n] = n * 24 + h * 2 + mh;   // mat=n (q,k,v), half=mh
                #pragma unroll
                for (int m = 0; m < 4; ++m)
                    acc[n][m] = (float4v){0.f, 0.f, 0.f, 0.f};
            }
            #pragma unroll
            for (int kk = 0; kk < 12; ++kk) {
                short8 aF[4];
                #pragma unroll
                for (int mt = 0; mt < 4; ++mt)
                    aF[mt] = *(const short8*)&xnp[((mt * 12 + kk) << 9) + (lane << 3)];
                short8 bF0 = *(const short8*)&wqp[((tile_[0] * 12 + kk) << 9) + (lane << 3)];
                short8 bF1 = *(const short8*)&wqp[((tile_[1] * 12 + kk) << 9) + (lane << 3)];
                short8 bF2 = *(const short8*)&wqp[((tile_[2] * 12 + kk) << 9) + (lane << 3)];
                #pragma unroll
                for (int mt = 0; mt < 4; ++mt) {
                    // q,k: swapped (C: row=dim-local, col=token) -> b64 scatter
                    acc[0][mt] = __builtin_amdgcn_mfma_f32_16x16x32_bf16(bF0, aF[mt], acc[0][mt], 0, 0, 0);
                    acc[1][mt] = __builtin_amdgcn_mfma_f32_16x16x32_bf16(bF1, aF[mt], acc[1][mt], 0, 0, 0);
                    // v: normal (C: row=token, col=dim) -> b64 vT scatter
                    acc[2][mt] = __builtin_amdgcn_mfma_f32_16x16x32_bf16(aF[mt], bF2, acc[2][mt], 0, 0, 0);
                }
            }
        }

        // ---------- PV(it-1): swapped (o = mfma(V, P)) + b64 attp write ----------
        if (it > 0) {
            const unsigned short* vpr = vp[(it - 1) & 1];
            float4v o[2][2];
            #pragma unroll
            for (int j = 0; j < 2; ++j)
                #pragma unroll
                for (int nt = 0; nt < 2; ++nt)
                    o[j][nt] = (float4v){0.f, 0.f, 0.f, 0.f};
            #pragma unroll
            for (int kk2 = 0; kk2 < 2; ++kk2) {
                #pragma unroll
                for (int nt = 0; nt < 2; ++nt) {
                    short8 vf = *(const short8*)&vpr[(((lh * 2 + nt) * 2 + kk2) << 9) + (lane << 3)];
                    #pragma unroll
                    for (int j = 0; j < 2; ++j)
                        o[j][nt] = __builtin_amdgcn_mfma_f32_16x16x32_bf16(vf, af[j][kk2], o[j][nt], 0, 0, 0);
                }
            }
            // o[j][nt]: row=dim 16nt+4l4+r, col=token 16(2mh+j)+lc
            #pragma unroll
            for (int j = 0; j < 2; ++j) {
                #pragma unroll
                for (int nt = 0; nt < 2; ++nt) {
                    const int addr = (((2 * mh + j) * 4 + lh) << 9)
                                   + (((2 * nt + (l4 >> 1)) * 16 + lc) << 3)
                                   + ((l4 & 1) << 2);
                    *(short4v*)&attp[addr] = pack4bf(o[j][nt][0], o[j][nt][1], o[j][nt][2], o[j][nt][3]);
                }
            }
        }

        // ---------- scatter(it): all b64 ----------
        if (it < 3) {
            unsigned short* vpw = vp[it & 1];
            #pragma unroll
            for (int mt = 0; mt < 4; ++mt) {
                short4v pq, pkk, pv;
                #pragma unroll
                for (int r = 0; r < 4; ++r) {
                    pq[r]  = (short)f2bf(acc[0][mt][r] * SCALEQ);
                    pkk[r] = (short)f2bf(acc[1][mt][r]);
                    pv[r]  = (short)f2bf(acc[2][mt][r]);
                }
                const int aqk = ((lh * 4 + mt) << 9)
                              + (((2 * mh + (l4 >> 1)) * 16 + lc) << 3)
                              + ((l4 & 1) << 2);
                *(short4v*)&qp[aqk] = pq;
                *(short4v*)&kp[aqk] = pkk;
                const int av = (((lh * 2 + mh) * 2 + (mt >> 1)) << 9)
                             + ((((mt & 1) * 2 + (l4 >> 1)) * 16 + lc) << 3)
                             + ((l4 & 1) << 2);
                *(short4v*)&vpw[av] = pv;
            }
        }
        __syncthreads();   // barrier 1: attp(it-1) + qkv(it) visible

        // ================= PHASE 2 (register outputs only) =================
        // ---------- GEMM2(it-1) with prefetched bGb ----------
        if (it > 0) {
            #pragma unroll
            for (int ks = 0; ks < 4; ++ks) {
                short8 aG[4];
                #pragma unroll
                for (int mt = 0; mt < 4; ++mt)
                    aG[mt] = *(const short8*)&attp[((mt * 4 + ks) << 9) + (lane << 3)];
                #pragma unroll
                for (int j2 = 0; j2 < 3; ++j2)
                    #pragma unroll
                    for (int mt = 0; mt < 4; ++mt)
                        facc[mt][j2] = __builtin_amdgcn_mfma_f32_16x16x32_bf16(aG[mt], bGb[ks][j2], facc[mt][j2], 0, 0, 0);
            }
        }
        // ---------- QK(it) + bias + rowmax ----------
        if (it < 3) {
            #pragma unroll
            for (int j = 0; j < 2; ++j) {
                short8 qf = *(const short8*)&qp[((lh * 4 + (2 * mh + j)) << 9) + (lane << 3)];
                #pragma unroll
                for (int kt = 0; kt < 4; ++kt) {
                    short8 kf = *(const short8*)&kp[((lh * 4 + kt) << 9) + (lane << 3)];
                    float4v sres = __builtin_amdgcn_mfma_f32_16x16x32_bf16(
                        kf, qf, (float4v){0.f, 0.f, 0.f, 0.f}, 0, 0, 0);
                    #pragma unroll
                    for (int r = 0; r < 4; ++r) sv[j][kt][r] = sres[r];
                }
            }
            #pragma unroll
            for (int j = 0; j < 2; ++j) {
                float m = -1e30f;
                #pragma unroll
                for (int kt = 0; kt < 4; ++kt) {
                    #pragma unroll
                    for (int r = 0; r < 4; ++r) {
                        sv[j][kt][r] += bbn[j][kt][r];
                        m = fmaxf(m, sv[j][kt][r]);
                    }
                }
                m = fmaxf(m, __shfl_xor(m, 16));
                m = fmaxf(m, __shfl_xor(m, 32));
                mx[j] = m;
            }
        }
        __syncthreads();   // barrier 2: attp/qp/kp reads done before next fused phase
    }

    // ---------------- epilogue ----------------
    {
        float* ob = out + b * (NTOK * CCH);
        #pragma unroll
        for (int mt = 0; mt < 4; ++mt) {
            #pragma unroll
            for (int j2 = 0; j2 < 3; ++j2) {
                const int c = 16 * (3 * wav + j2) + lc;
                const float bo = b_out[c];
                #pragma unroll
                for (int r = 0; r < 4; ++r)
                    ob[(16 * mt + 4 * l4 + r) * CCH + c] = facc[mt][j2][r] + bo;
            }
        }
    }
}

extern "C" void kernel_launch(void* const* d_in, const int* in_sizes, int n_in,
                              void* d_out, int out_size, void* d_ws, size_t ws_size,
                              hipStream_t stream) {
    const float* x     = (const float*)d_in[0];
    const float* ln_g  = (const float*)d_in[1];
    const float* ln_b  = (const float*)d_in[2];
    const float* w_qkv = (const float*)d_in[3];
    const float* w_out = (const float*)d_in[4];
    const float* b_out = (const float*)d_in[5];
    const float* btab  = (const float*)d_in[6];
    const int*   ridx  = (const int*)d_in[7];
    float*       out   = (float*)d_out;

    unsigned short* wqp   = (unsigned short*)d_ws;
    unsigned short* wop   = wqp + WQP_ELEMS;
    float*          blutp = (float*)(wop + WOP_ELEMS);   // byte offset 1179648, 16B-aligned

    prep_kernel<<<512, 256, 0, stream>>>(w_qkv, w_out, btab, ridx, wqp, wop, blutp);
    fused_win_mha<<<2048, 512, 0, stream>>>(x, ln_g, ln_b, b_out, wqp, wop, blutp, out);
}